// Round 1
// baseline (1532.019 us; speedup 1.0000x reference)
//
#include <hip/hip_runtime.h>
#include <math.h>

// Problem constants
#define T_SEQ 28
#define D_IN  28
#define H     128
#define G4    512          // 4*H
#define BT    32           // batch rows per block
#define NTHR  512          // 8 waves
#define HS    36           // LDS row stride (pad 32 -> 36: 2-way max bank aliasing = free)

#define NW0 (156*512)      // Wr0: rows 0..27 = W_ih0^T, 28..155 = W_hh0^T, cols j*4+gt
#define NW1 (256*512)      // Wr1: rows 0..127 = W_ih1^T, 128..255 = W_hh1^T

__device__ __forceinline__ float sigm(float x)   { return 1.0f / (1.0f + __expf(-x)); }
__device__ __forceinline__ float tanh_f(float x) { return 1.0f - 2.0f / (1.0f + __expf(2.0f * x)); }

// Rearrange weights: Wr[k][j*4+gt] = W[gt*128+j][k-part], biases combined (b_ih+b_hh)
__global__ void prep_kernel(const float* __restrict__ Wih0, const float* __restrict__ Whh0,
                            const float* __restrict__ bih0, const float* __restrict__ bhh0,
                            const float* __restrict__ Wih1, const float* __restrict__ Whh1,
                            const float* __restrict__ bih1, const float* __restrict__ bhh1,
                            float* __restrict__ ws) {
    int i = blockIdx.x * blockDim.x + threadIdx.x;
    if (i < NW0) {
        int k = i >> 9, col = i & 511;
        int j = col >> 2, gt = col & 3, g = gt * H + j;
        ws[i] = (k < D_IN) ? Wih0[g * D_IN + k] : Whh0[g * H + (k - D_IN)];
    } else if (i < NW0 + NW1) {
        int r = i - NW0;
        int k = r >> 9, col = r & 511;
        int j = col >> 2, gt = col & 3, g = gt * H + j;
        ws[i] = (k < H) ? Wih1[g * H + k] : Whh1[g * H + (k - H)];
    } else if (i < NW0 + NW1 + 512) {
        int col = i - NW0 - NW1;
        int j = col >> 2, gt = col & 3, g = gt * H + j;
        ws[i] = bih0[g] + bhh0[g];
    } else if (i < NW0 + NW1 + 1024) {
        int col = i - NW0 - NW1 - 512;
        int j = col >> 2, gt = col & 3, g = gt * H + j;
        ws[i] = bih1[g] + bhh1[g];
    }
}

// acc[(jj*4+gt)*4+bi]: gates for units j2+jj (jj<2), gate type gt, batch b4+bi
__device__ __forceinline__ void fma_tile(float acc[32], float4 w0, float4 w1, float4 v) {
    float wv[8] = {w0.x, w0.y, w0.z, w0.w, w1.x, w1.y, w1.z, w1.w};
    float vv[4] = {v.x, v.y, v.z, v.w};
#pragma unroll
    for (int g = 0; g < 8; ++g)
#pragma unroll
        for (int bi = 0; bi < 4; ++bi)
            acc[g * 4 + bi] += wv[g] * vv[bi];
}

__global__ __launch_bounds__(NTHR, 2) void lstm_fused(
    const float* __restrict__ x, const float* __restrict__ ws,
    const float* __restrict__ Wfc, const float* __restrict__ bfc,
    float* __restrict__ out) {
    __shared__ __align__(16) float xv[D_IN * HS];
    __shared__ __align__(16) float h0[H * HS];
    __shared__ __align__(16) float h1[H * HS];

    const float* Wr0 = ws;
    const float* Wr1 = ws + NW0;
    const float* br0 = ws + NW0 + NW1;
    const float* br1 = br0 + 512;

    const int tid = threadIdx.x;
    const int b4 = (tid & 7) << 2;   // batch sub-tile base (0,4,...,28)
    const int jg = tid >> 3;         // 0..63
    const int j2 = jg << 1;          // hidden-unit pair base

    for (int i = tid; i < H * HS; i += NTHR) { h0[i] = 0.f; h1[i] = 0.f; }

    float c0r[8], c1r[8];            // cell state, [jj*4+bi] — lives in registers
#pragma unroll
    for (int i = 0; i < 8; ++i) { c0r[i] = 0.f; c1r[i] = 0.f; }

    float bv0[8], bv1[8];
#pragma unroll
    for (int i = 0; i < 8; ++i) { bv0[i] = br0[j2 * 4 + i]; bv1[i] = br1[j2 * 4 + i]; }

    const int bbase = blockIdx.x * BT;
    const float* xblk = x + (size_t)bbase * (T_SEQ * D_IN);
    const float* wp0 = Wr0 + j2 * 4;
    const float* wp1 = Wr1 + j2 * 4;

    __syncthreads();

    for (int t = 0; t < T_SEQ; ++t) {
        // ---- stage x_t into xv[d][b] (transposed) ----
        if (tid < 224) {
            int b = tid / 7, q = tid % 7;
            float4 xx = *(const float4*)&xblk[(size_t)b * (T_SEQ * D_IN) + t * D_IN + q * 4];
            xv[(q * 4 + 0) * HS + b] = xx.x;
            xv[(q * 4 + 1) * HS + b] = xx.y;
            xv[(q * 4 + 2) * HS + b] = xx.z;
            xv[(q * 4 + 3) * HS + b] = xx.w;
        }
        __syncthreads();

        // ---- layer 0 gates: K = 28 (x) + 128 (h0) ----
        float acc[32];
#pragma unroll
        for (int i = 0; i < 8; ++i) {
            acc[i * 4 + 0] = bv0[i]; acc[i * 4 + 1] = bv0[i];
            acc[i * 4 + 2] = bv0[i]; acc[i * 4 + 3] = bv0[i];
        }
#pragma unroll 4
        for (int k = 0; k < D_IN; ++k) {
            float4 v4 = *(const float4*)&xv[k * HS + b4];
            float4 w0 = *(const float4*)&wp0[k * 512];
            float4 w1 = *(const float4*)&wp0[k * 512 + 4];
            fma_tile(acc, w0, w1, v4);
        }
#pragma unroll 4
        for (int k = 0; k < H; ++k) {
            float4 v4 = *(const float4*)&h0[k * HS + b4];
            float4 w0 = *(const float4*)&wp0[(k + D_IN) * 512];
            float4 w1 = *(const float4*)&wp0[(k + D_IN) * 512 + 4];
            fma_tile(acc, w0, w1, v4);
        }
        __syncthreads();   // all GEMM0 reads of h0/xv done

        // ---- elementwise L0 (c in registers), write h0_new ----
#pragma unroll
        for (int jj = 0; jj < 2; ++jj) {
            float hv[4];
#pragma unroll
            for (int bi = 0; bi < 4; ++bi) {
                float ig = sigm(acc[(jj * 4 + 0) * 4 + bi]);
                float fg = sigm(acc[(jj * 4 + 1) * 4 + bi]);
                float gg = tanh_f(acc[(jj * 4 + 2) * 4 + bi]);
                float og = sigm(acc[(jj * 4 + 3) * 4 + bi]);
                float c = fg * c0r[jj * 4 + bi] + ig * gg;
                c0r[jj * 4 + bi] = c;
                hv[bi] = og * tanh_f(c);
            }
            *(float4*)&h0[(j2 + jj) * HS + b4] = make_float4(hv[0], hv[1], hv[2], hv[3]);
        }
        __syncthreads();   // h0_new visible

        // ---- layer 1 gates: K = 128 (h0_new) + 128 (h1) ----
#pragma unroll
        for (int i = 0; i < 8; ++i) {
            acc[i * 4 + 0] = bv1[i]; acc[i * 4 + 1] = bv1[i];
            acc[i * 4 + 2] = bv1[i]; acc[i * 4 + 3] = bv1[i];
        }
#pragma unroll 4
        for (int k = 0; k < H; ++k) {
            float4 v4 = *(const float4*)&h0[k * HS + b4];
            float4 w0 = *(const float4*)&wp1[k * 512];
            float4 w1 = *(const float4*)&wp1[k * 512 + 4];
            fma_tile(acc, w0, w1, v4);
        }
#pragma unroll 4
        for (int k = 0; k < H; ++k) {
            float4 v4 = *(const float4*)&h1[k * HS + b4];
            float4 w0 = *(const float4*)&wp1[(k + H) * 512];
            float4 w1 = *(const float4*)&wp1[(k + H) * 512 + 4];
            fma_tile(acc, w0, w1, v4);
        }
        __syncthreads();   // all GEMM1 reads of h0/h1 done

#pragma unroll
        for (int jj = 0; jj < 2; ++jj) {
            float hv[4];
#pragma unroll
            for (int bi = 0; bi < 4; ++bi) {
                float ig = sigm(acc[(jj * 4 + 0) * 4 + bi]);
                float fg = sigm(acc[(jj * 4 + 1) * 4 + bi]);
                float gg = tanh_f(acc[(jj * 4 + 2) * 4 + bi]);
                float og = sigm(acc[(jj * 4 + 3) * 4 + bi]);
                float c = fg * c1r[jj * 4 + bi] + ig * gg;
                c1r[jj * 4 + bi] = c;
                hv[bi] = og * tanh_f(c);
            }
            *(float4*)&h1[(j2 + jj) * HS + b4] = make_float4(hv[0], hv[1], hv[2], hv[3]);
        }
        // h1_new protected by next iteration's syncs before any GEMM1 read
    }

    __syncthreads();   // final h1 visible

    // ---- FC (10x128) + log_softmax ----
    if (tid < 320) {
        int c = tid >> 5, b = tid & 31;
        float s = bfc[c];
        const float* wr = Wfc + c * H;
#pragma unroll 4
        for (int j = 0; j < H; ++j) s = fmaf(wr[j], h1[j * HS + b], s);
        xv[c * 32 + b] = s;   // reuse xv as logits buffer
    }
    __syncthreads();
    if (tid < 32) {
        int b = tid;
        float m = -1e30f;
#pragma unroll
        for (int c = 0; c < 10; ++c) m = fmaxf(m, xv[c * 32 + b]);
        float ssum = 0.f;
#pragma unroll
        for (int c = 0; c < 10; ++c) ssum += __expf(xv[c * 32 + b] - m);
        float ls = m + __logf(ssum);
        float* op = out + (size_t)(bbase + b) * 10;
#pragma unroll
        for (int c = 0; c < 10; ++c) op[c] = xv[c * 32 + b] - ls;
    }
}

extern "C" void kernel_launch(void* const* d_in, const int* in_sizes, int n_in,
                              void* d_out, int out_size, void* d_ws, size_t ws_size,
                              hipStream_t stream) {
    const float* x    = (const float*)d_in[0];
    const float* Wih0 = (const float*)d_in[1];
    const float* Whh0 = (const float*)d_in[2];
    const float* bih0 = (const float*)d_in[3];
    const float* bhh0 = (const float*)d_in[4];
    const float* Wih1 = (const float*)d_in[5];
    const float* Whh1 = (const float*)d_in[6];
    const float* bih1 = (const float*)d_in[7];
    const float* bhh1 = (const float*)d_in[8];
    const float* Wfc  = (const float*)d_in[9];
    const float* bfc  = (const float*)d_in[10];
    float* out = (float*)d_out;
    float* ws  = (float*)d_ws;

    const int n_prep = NW0 + NW1 + 1024;
    prep_kernel<<<(n_prep + 255) / 256, 256, 0, stream>>>(Wih0, Whh0, bih0, bhh0,
                                                          Wih1, Whh1, bih1, bhh1, ws);
    lstm_fused<<<8192 / BT, NTHR, 0, stream>>>(x, ws, Wfc, bfc, out);
}

// Round 2
// 433.361 us; speedup vs baseline: 3.5352x; 3.5352x over previous
//
#include <hip/hip_runtime.h>
#include <math.h>

#define T_SEQ 28
#define D_IN  28
#define H     128
#define BT    32           // batch rows per block (2 M-tiles of 16)
#define NTHR  512          // 8 waves; wave ut owns 16 units x 4 gate types

typedef short bf16x8 __attribute__((ext_vector_type(8)));   // 8 bf16 = 4 VGPR (A/B frag)
typedef float f32x4  __attribute__((ext_vector_type(4)));   // C/D frag

// ws layout: W0 frags [ut][f0:20][lane][8] | W1 frags [ut][f1:32][lane][8] | biases fp32
#define NW0E (8*20*512)                     // 81920 ushorts
#define NW1E (8*32*512)                     // 131072 ushorts
#define BIAS_OFF_BYTES ((NW0E + NW1E) * 2)  // 425984 B, 16-aligned

__device__ __forceinline__ unsigned short f2bf(float f) {
    unsigned u = __float_as_uint(f);
    u += 0x7fffu + ((u >> 16) & 1u);        // round-to-nearest-even
    return (unsigned short)(u >> 16);
}
__device__ __forceinline__ float bf2f(unsigned short h) {
    return __uint_as_float(((unsigned)h) << 16);
}
__device__ __forceinline__ float sigm(float x)   { return 1.0f / (1.0f + __expf(-x)); }
__device__ __forceinline__ float tanhf_(float x) { return 1.0f - 2.0f / (1.0f + __expf(2.0f * x)); }

#define MFMA(acc, a, b) acc = __builtin_amdgcn_mfma_f32_16x16x32_bf16(a, b, acc, 0, 0, 0)

// Pack weights into exact B-fragment order: B[k][n], n = lane&15 (gate col within
// tile), k = (lane>>4)*8 + j.  Gate col g = gt*128 + ut*16 + n (PyTorch i,f,g,o order).
__global__ void prep(const float* __restrict__ Wih0, const float* __restrict__ Whh0,
                     const float* __restrict__ bih0, const float* __restrict__ bhh0,
                     const float* __restrict__ Wih1, const float* __restrict__ Whh1,
                     const float* __restrict__ bih1, const float* __restrict__ bhh1,
                     unsigned short* __restrict__ W, float* __restrict__ bias) {
    int i = blockIdx.x * 256 + threadIdx.x;
    if (i < NW0E) {
        int ut = i / (20*512), r = i % (20*512);
        int f = r >> 9, e = r & 511;
        int lane = e >> 3, j = e & 7;
        int lrow = lane & 15, quad = lane >> 4;
        float v;
        if (f < 4) {                        // x-part: 1 K-step (K=28 padded to 32)
            int gt = f, k = quad*8 + j;
            int g = gt*128 + ut*16 + lrow;
            v = (k < D_IN) ? Wih0[g*D_IN + k] : 0.0f;
        } else {                            // h0-part: 4 K-steps
            int ks = (f-4) >> 2, gt = (f-4) & 3;
            int g = gt*128 + ut*16 + lrow;
            v = Whh0[g*H + ks*32 + quad*8 + j];
        }
        W[i] = f2bf(v);
    } else if (i < NW0E + NW1E) {
        int i2 = i - NW0E;
        int ut = i2 / (32*512), r = i2 % (32*512);
        int f = r >> 9, e = r & 511;
        int lane = e >> 3, j = e & 7;
        int lrow = lane & 15, quad = lane >> 4;
        int ks = f >> 2, gt = f & 3;        // ks 0..3 = h0 input (Wih1), 4..7 = h1 rec (Whh1)
        int g = gt*128 + ut*16 + lrow;
        float v = (ks < 4) ? Wih1[g*H + ks*32 + quad*8 + j]
                           : Whh1[g*H + (ks-4)*32 + quad*8 + j];
        W[i] = f2bf(v);
    } else if (i < NW0E + NW1E + 1024) {
        int g = i - NW0E - NW1E;
        if (g < 512) bias[g] = bih0[g] + bhh0[g];
        else         bias[g] = bih1[g-512] + bhh1[g-512];
    }
}

// h LDS layout: [b:32][128] bf16, XOR-swizzled 16B chunks: element (b,k) at
// b*128 + ((k>>3) ^ (b&15))*8 + (k&7).  A-frag read = one aligned ds_read_b128.
__global__ __launch_bounds__(NTHR, 2) void lstm_mfma(
    const float* __restrict__ x, const unsigned short* __restrict__ W,
    const float* __restrict__ bias,
    const float* __restrict__ Wfc, const float* __restrict__ bfc,
    float* __restrict__ out)
{
    __shared__ __align__(16) unsigned short h0s[32*128];
    __shared__ __align__(16) unsigned short h1s[32*128];
    __shared__ float lg[320];

    const int tid  = threadIdx.x;
    const int lane = tid & 63;
    const int ut   = tid >> 6;      // wave id = unit-tile (16 units)
    const int lrow = lane & 15;
    const int quad = lane >> 4;
    const int bbase = blockIdx.x * BT;

    for (int i = tid; i < 32*128; i += NTHR) { h0s[i] = 0; h1s[i] = 0; }

    float c0[2][4], c1[2][4];       // cell state fp32: [Mtile][reg], unit=ut*16+lrow
#pragma unroll
    for (int m = 0; m < 2; ++m)
#pragma unroll
        for (int r = 0; r < 4; ++r) { c0[m][r] = 0.f; c1[m][r] = 0.f; }

    float bv0[4], bv1[4];
#pragma unroll
    for (int gt = 0; gt < 4; ++gt) {
        bv0[gt] = bias[gt*128 + ut*16 + lrow];
        bv1[gt] = bias[512 + gt*128 + ut*16 + lrow];
    }

    const unsigned short* w0p = W + ut*(20*512) + lane*8;           // frag f: +f*512
    const unsigned short* w1p = W + NW0E + ut*(32*512) + lane*8;

    const float* xr0 = x + (size_t)(bbase + lrow)      * (T_SEQ*D_IN) + quad*8;
    const float* xr1 = x + (size_t)(bbase + 16 + lrow) * (T_SEQ*D_IN) + quad*8;

    __syncthreads();

    for (int t = 0; t < T_SEQ; ++t) {
        f32x4 acc[2][4];
#pragma unroll
        for (int gt = 0; gt < 4; ++gt) {
            f32x4 s = {bv0[gt], bv0[gt], bv0[gt], bv0[gt]};
            acc[0][gt] = s; acc[1][gt] = s;
        }

        // ---- layer0, ks=0: x contribution (K 0..31, zeros past 27) ----
        {
            const float* p0 = xr0 + t*D_IN;
            const float* p1 = xr1 + t*D_IN;
            float4 lo0 = *(const float4*)p0;
            float4 lo1 = *(const float4*)p1;
            float4 hi0 = make_float4(0,0,0,0), hi1 = make_float4(0,0,0,0);
            if (quad < 3) { hi0 = *(const float4*)(p0+4); hi1 = *(const float4*)(p1+4); }
            bf16x8 a0, a1;
            a0[0]=f2bf(lo0.x); a0[1]=f2bf(lo0.y); a0[2]=f2bf(lo0.z); a0[3]=f2bf(lo0.w);
            a0[4]=f2bf(hi0.x); a0[5]=f2bf(hi0.y); a0[6]=f2bf(hi0.z); a0[7]=f2bf(hi0.w);
            a1[0]=f2bf(lo1.x); a1[1]=f2bf(lo1.y); a1[2]=f2bf(lo1.z); a1[3]=f2bf(lo1.w);
            a1[4]=f2bf(hi1.x); a1[5]=f2bf(hi1.y); a1[6]=f2bf(hi1.z); a1[7]=f2bf(hi1.w);
#pragma unroll
            for (int gt = 0; gt < 4; ++gt) {
                bf16x8 bf = *(const bf16x8*)(w0p + gt*512);
                MFMA(acc[0][gt], a0, bf);
                MFMA(acc[1][gt], a1, bf);
            }
        }
        // ---- layer0, ks 1..4: h0 recurrence ----
#pragma unroll
        for (int ks = 0; ks < 4; ++ks) {
            int cc = ks*4 + quad;
            bf16x8 a0 = *(const bf16x8*)&h0s[lrow*128      + ((cc ^ lrow)*8)];
            bf16x8 a1 = *(const bf16x8*)&h0s[(16+lrow)*128 + ((cc ^ lrow)*8)];
#pragma unroll
            for (int gt = 0; gt < 4; ++gt) {
                bf16x8 bf = *(const bf16x8*)(w0p + (4 + ks*4 + gt)*512);
                MFMA(acc[0][gt], a0, bf);
                MFMA(acc[1][gt], a1, bf);
            }
        }
        __syncthreads();   // all h0s/x reads done before h0s rewrite

        // ---- elementwise L0 (c in regs) -> h0s ----
#pragma unroll
        for (int m = 0; m < 2; ++m) {
#pragma unroll
            for (int r = 0; r < 4; ++r) {
                float ig = sigm(acc[m][0][r]);
                float fg = sigm(acc[m][1][r]);
                float gg = tanhf_(acc[m][2][r]);
                float og = sigm(acc[m][3][r]);
                float c  = fg * c0[m][r] + ig * gg;
                c0[m][r] = c;
                float h  = og * tanhf_(c);
                int b = m*16 + quad*4 + r;
                int j = ut*16 + lrow;
                h0s[b*128 + (((j>>3) ^ (b&15))*8) + (j&7)] = f2bf(h);
            }
        }
        __syncthreads();   // h0_new visible

        // ---- layer1: ks 0..3 read h0_new, ks 4..7 read h1_old ----
#pragma unroll
        for (int gt = 0; gt < 4; ++gt) {
            f32x4 s = {bv1[gt], bv1[gt], bv1[gt], bv1[gt]};
            acc[0][gt] = s; acc[1][gt] = s;
        }
#pragma unroll
        for (int ks = 0; ks < 8; ++ks) {
            int cc = (ks & 3)*4 + quad;
            const unsigned short* hs = (ks < 4) ? h0s : h1s;
            bf16x8 a0 = *(const bf16x8*)&hs[lrow*128      + ((cc ^ lrow)*8)];
            bf16x8 a1 = *(const bf16x8*)&hs[(16+lrow)*128 + ((cc ^ lrow)*8)];
#pragma unroll
            for (int gt = 0; gt < 4; ++gt) {
                bf16x8 bf = *(const bf16x8*)(w1p + (ks*4 + gt)*512);
                MFMA(acc[0][gt], a0, bf);
                MFMA(acc[1][gt], a1, bf);
            }
        }
        __syncthreads();   // all h0s/h1s reads done before h1s rewrite

        // ---- elementwise L1 -> h1s (no barrier needed after; next-t L0 doesn't touch h1s) ----
#pragma unroll
        for (int m = 0; m < 2; ++m) {
#pragma unroll
            for (int r = 0; r < 4; ++r) {
                float ig = sigm(acc[m][0][r]);
                float fg = sigm(acc[m][1][r]);
                float gg = tanhf_(acc[m][2][r]);
                float og = sigm(acc[m][3][r]);
                float c  = fg * c1[m][r] + ig * gg;
                c1[m][r] = c;
                float h  = og * tanhf_(c);
                int b = m*16 + quad*4 + r;
                int j = ut*16 + lrow;
                h1s[b*128 + (((j>>3) ^ (b&15))*8) + (j&7)] = f2bf(h);
            }
        }
    }

    __syncthreads();   // final h1 visible

    // ---- FC (10x128) + log_softmax ----
    if (tid < 320) {
        int c = tid >> 5, b = tid & 31;
        float s = bfc[c];
        const float* wr = Wfc + c*H;
#pragma unroll 4
        for (int j = 0; j < H; ++j)
            s = fmaf(wr[j], bf2f(h1s[b*128 + (((j>>3) ^ (b&15))*8) + (j&7)]), s);
        lg[c*32 + b] = s;
    }
    __syncthreads();
    if (tid < 32) {
        int b = tid;
        float m = -1e30f;
#pragma unroll
        for (int c = 0; c < 10; ++c) m = fmaxf(m, lg[c*32 + b]);
        float ssum = 0.f;
#pragma unroll
        for (int c = 0; c < 10; ++c) ssum += __expf(lg[c*32 + b] - m);
        float ls = m + __logf(ssum);
        float* op = out + (size_t)(bbase + b) * 10;
#pragma unroll
        for (int c = 0; c < 10; ++c) op[c] = lg[c*32 + b] - ls;
    }
}

extern "C" void kernel_launch(void* const* d_in, const int* in_sizes, int n_in,
                              void* d_out, int out_size, void* d_ws, size_t ws_size,
                              hipStream_t stream) {
    const float* x    = (const float*)d_in[0];
    const float* Wih0 = (const float*)d_in[1];
    const float* Whh0 = (const float*)d_in[2];
    const float* bih0 = (const float*)d_in[3];
    const float* bhh0 = (const float*)d_in[4];
    const float* Wih1 = (const float*)d_in[5];
    const float* Whh1 = (const float*)d_in[6];
    const float* bih1 = (const float*)d_in[7];
    const float* bhh1 = (const float*)d_in[8];
    const float* Wfc  = (const float*)d_in[9];
    const float* bfc  = (const float*)d_in[10];
    float* out = (float*)d_out;

    unsigned short* W = (unsigned short*)d_ws;
    float* bias = (float*)((char*)d_ws + BIAS_OFF_BYTES);

    const int n_prep = NW0E + NW1E + 1024;
    prep<<<(n_prep + 255) / 256, 256, 0, stream>>>(Wih0, Whh0, bih0, bhh0,
                                                   Wih1, Whh1, bih1, bhh1, W, bias);
    lstm_mfma<<<8192 / BT, NTHR, 0, stream>>>(x, W, bias, Wfc, bfc, out);
}

// Round 3
// 308.883 us; speedup vs baseline: 4.9599x; 1.4030x over previous
//
#include <hip/hip_runtime.h>
#include <math.h>

#define T_SEQ 28
#define D_IN  28
#define H     128
#define BT    32           // batch rows per block (2 M-tiles of 16)
#define NTHR  512          // 8 waves; wave ut owns 16 units x 4 gate types

typedef short bf16x8 __attribute__((ext_vector_type(8)));   // 8 bf16 = 4 VGPR (A/B frag)
typedef float f32x4  __attribute__((ext_vector_type(4)));   // C/D frag

// ws layout: W0 frags [ut][f0:20][lane][8] | W1 frags [ut][f1:32][lane][8] | biases fp32
#define NW0E (8*20*512)                     // 81920 ushorts
#define NW1E (8*32*512)                     // 131072 ushorts
#define BIAS_OFF_BYTES ((NW0E + NW1E) * 2)  // 425984 B, 16-aligned

__device__ __forceinline__ unsigned short f2bf(float f) {
    unsigned u = __float_as_uint(f);
    u += 0x7fffu + ((u >> 16) & 1u);        // round-to-nearest-even
    return (unsigned short)(u >> 16);
}
__device__ __forceinline__ float bf2f(unsigned short h) {
    return __uint_as_float(((unsigned)h) << 16);
}
__device__ __forceinline__ float sigm(float x)   { return 1.0f / (1.0f + __expf(-x)); }
__device__ __forceinline__ float tanhf_(float x) { return 1.0f - 2.0f / (1.0f + __expf(2.0f * x)); }

#define MFMA(acc, a, b) acc = __builtin_amdgcn_mfma_f32_16x16x32_bf16(a, b, acc, 0, 0, 0)

// Pack weights into exact B-fragment order: B[k][n], n = lane&15 (gate col within
// tile), k = (lane>>4)*8 + j.  Gate col g = gt*128 + ut*16 + n (PyTorch i,f,g,o order).
__global__ void prep(const float* __restrict__ Wih0, const float* __restrict__ Whh0,
                     const float* __restrict__ bih0, const float* __restrict__ bhh0,
                     const float* __restrict__ Wih1, const float* __restrict__ Whh1,
                     const float* __restrict__ bih1, const float* __restrict__ bhh1,
                     unsigned short* __restrict__ W, float* __restrict__ bias) {
    int i = blockIdx.x * 256 + threadIdx.x;
    if (i < NW0E) {
        int ut = i / (20*512), r = i % (20*512);
        int f = r >> 9, e = r & 511;
        int lane = e >> 3, j = e & 7;
        int lrow = lane & 15, quad = lane >> 4;
        float v;
        if (f < 4) {                        // x-part: 1 K-step (K=28 padded to 32)
            int gt = f, k = quad*8 + j;
            int g = gt*128 + ut*16 + lrow;
            v = (k < D_IN) ? Wih0[g*D_IN + k] : 0.0f;
        } else {                            // h0-part: 4 K-steps
            int ks = (f-4) >> 2, gt = (f-4) & 3;
            int g = gt*128 + ut*16 + lrow;
            v = Whh0[g*H + ks*32 + quad*8 + j];
        }
        W[i] = f2bf(v);
    } else if (i < NW0E + NW1E) {
        int i2 = i - NW0E;
        int ut = i2 / (32*512), r = i2 % (32*512);
        int f = r >> 9, e = r & 511;
        int lane = e >> 3, j = e & 7;
        int lrow = lane & 15, quad = lane >> 4;
        int ks = f >> 2, gt = f & 3;        // ks 0..3 = h0 input (Wih1), 4..7 = h1 rec (Whh1)
        int g = gt*128 + ut*16 + lrow;
        float v = (ks < 4) ? Wih1[g*H + ks*32 + quad*8 + j]
                           : Whh1[g*H + (ks-4)*32 + quad*8 + j];
        W[i] = f2bf(v);
    } else if (i < NW0E + NW1E + 1024) {
        int g = i - NW0E - NW1E;
        if (g < 512) bias[g] = bih0[g] + bhh0[g];
        else         bias[g] = bih1[g-512] + bhh1[g-512];
    }
}

// h LDS layout: [b:32][128] bf16, XOR-swizzled 16B chunks: element (b,k) at
// b*128 + ((k>>3) ^ (b&15))*8 + (k&7).  A-frag read = one aligned ds_read_b128.
// Weights: 36 frags/wave in VGPRs (loaded once), 16 frags/wave (W1 ks4..7) in LDS.
__global__ __launch_bounds__(NTHR, 1) void lstm_mfma(
    const float* __restrict__ x, const unsigned short* __restrict__ W,
    const float* __restrict__ bias,
    const float* __restrict__ Wfc, const float* __restrict__ bfc,
    float* __restrict__ out)
{
    __shared__ __align__(16) unsigned short h0s[32*128];   //  8 KB
    __shared__ __align__(16) unsigned short h1s[32*128];   //  8 KB
    __shared__ __align__(16) unsigned short wl[8*16*512];  // 128 KB: W1 ks4..7 frags
    __shared__ float lg[320];

    const int tid  = threadIdx.x;
    const int lane = tid & 63;
    const int ut   = tid >> 6;      // wave id = unit-tile (16 units)
    const int lrow = lane & 15;
    const int quad = lane >> 4;
    const int bbase = blockIdx.x * BT;

    for (int i = tid; i < 32*128; i += NTHR) { h0s[i] = 0; h1s[i] = 0; }

    // ---- stage W1 ks4..7 (Whh1) fragments into LDS, once ----
#pragma unroll
    for (int it = 0; it < 16; ++it) {
        int i = it * (NTHR*8) + tid*8;
        int utw = i >> 13, r = i & 8191;
        *(bf16x8*)&wl[i] = *(const bf16x8*)&W[NW0E + utw*16384 + 8192 + r];
    }

    // ---- load 36 weight fragments into registers, once ----
    const unsigned short* w0p = W + ut*(20*512) + lane*8;
    const unsigned short* w1p = W + NW0E + ut*(32*512) + lane*8;
    bf16x8 w0x[4], w0h[16], w1h[16];
#pragma unroll
    for (int f = 0; f < 4; ++f)  w0x[f] = *(const bf16x8*)(w0p + f*512);
#pragma unroll
    for (int f = 0; f < 16; ++f) w0h[f] = *(const bf16x8*)(w0p + (4+f)*512);
#pragma unroll
    for (int f = 0; f < 16; ++f) w1h[f] = *(const bf16x8*)(w1p + f*512);

    float c0[2][4], c1[2][4];       // cell state fp32: [Mtile][reg], unit=ut*16+lrow
#pragma unroll
    for (int m = 0; m < 2; ++m)
#pragma unroll
        for (int r = 0; r < 4; ++r) { c0[m][r] = 0.f; c1[m][r] = 0.f; }

    float bv0[4], bv1[4];
#pragma unroll
    for (int gt = 0; gt < 4; ++gt) {
        bv0[gt] = bias[gt*128 + ut*16 + lrow];
        bv1[gt] = bias[512 + gt*128 + ut*16 + lrow];
    }

    const float* xr0 = x + (size_t)(bbase + lrow)      * (T_SEQ*D_IN) + quad*8;
    const float* xr1 = x + (size_t)(bbase + 16 + lrow) * (T_SEQ*D_IN) + quad*8;

    __syncthreads();

    for (int t = 0; t < T_SEQ; ++t) {
        f32x4 acc[2][4];
#pragma unroll
        for (int gt = 0; gt < 4; ++gt) {
            f32x4 s = {bv0[gt], bv0[gt], bv0[gt], bv0[gt]};
            acc[0][gt] = s; acc[1][gt] = s;
        }

        // ---- layer0, ks=0: x contribution (K 0..31, zeros past 27) ----
        {
            const float* p0 = xr0 + t*D_IN;
            const float* p1 = xr1 + t*D_IN;
            float4 lo0 = *(const float4*)p0;
            float4 lo1 = *(const float4*)p1;
            float4 hi0 = make_float4(0,0,0,0), hi1 = make_float4(0,0,0,0);
            if (quad < 3) { hi0 = *(const float4*)(p0+4); hi1 = *(const float4*)(p1+4); }
            bf16x8 a0, a1;
            a0[0]=f2bf(lo0.x); a0[1]=f2bf(lo0.y); a0[2]=f2bf(lo0.z); a0[3]=f2bf(lo0.w);
            a0[4]=f2bf(hi0.x); a0[5]=f2bf(hi0.y); a0[6]=f2bf(hi0.z); a0[7]=f2bf(hi0.w);
            a1[0]=f2bf(lo1.x); a1[1]=f2bf(lo1.y); a1[2]=f2bf(lo1.z); a1[3]=f2bf(lo1.w);
            a1[4]=f2bf(hi1.x); a1[5]=f2bf(hi1.y); a1[6]=f2bf(hi1.z); a1[7]=f2bf(hi1.w);
#pragma unroll
            for (int gt = 0; gt < 4; ++gt) {
                MFMA(acc[0][gt], a0, w0x[gt]);
                MFMA(acc[1][gt], a1, w0x[gt]);
            }
        }
        // ---- layer0, ks 1..4: h0 recurrence (weights in regs) ----
#pragma unroll
        for (int ks = 0; ks < 4; ++ks) {
            int cc = ks*4 + quad;
            bf16x8 a0 = *(const bf16x8*)&h0s[lrow*128      + ((cc ^ lrow)*8)];
            bf16x8 a1 = *(const bf16x8*)&h0s[(16+lrow)*128 + ((cc ^ lrow)*8)];
#pragma unroll
            for (int gt = 0; gt < 4; ++gt) {
                MFMA(acc[0][gt], a0, w0h[ks*4+gt]);
                MFMA(acc[1][gt], a1, w0h[ks*4+gt]);
            }
        }
        __syncthreads();   // all h0s/x reads done before h0s rewrite

        // ---- elementwise L0 (c in regs) -> h0s ----
#pragma unroll
        for (int m = 0; m < 2; ++m) {
#pragma unroll
            for (int r = 0; r < 4; ++r) {
                float ig = sigm(acc[m][0][r]);
                float fg = sigm(acc[m][1][r]);
                float gg = tanhf_(acc[m][2][r]);
                float og = sigm(acc[m][3][r]);
                float c  = fg * c0[m][r] + ig * gg;
                c0[m][r] = c;
                float h  = og * tanhf_(c);
                int b = m*16 + quad*4 + r;
                int j = ut*16 + lrow;
                h0s[b*128 + (((j>>3) ^ (b&15))*8) + (j&7)] = f2bf(h);
            }
        }
        __syncthreads();   // h0_new visible

        // ---- layer1: ks 0..3 read h0_new (regs W), ks 4..7 read h1_old (LDS W) ----
#pragma unroll
        for (int gt = 0; gt < 4; ++gt) {
            f32x4 s = {bv1[gt], bv1[gt], bv1[gt], bv1[gt]};
            acc[0][gt] = s; acc[1][gt] = s;
        }
#pragma unroll
        for (int ks = 0; ks < 4; ++ks) {
            int cc = ks*4 + quad;
            bf16x8 a0 = *(const bf16x8*)&h0s[lrow*128      + ((cc ^ lrow)*8)];
            bf16x8 a1 = *(const bf16x8*)&h0s[(16+lrow)*128 + ((cc ^ lrow)*8)];
#pragma unroll
            for (int gt = 0; gt < 4; ++gt) {
                MFMA(acc[0][gt], a0, w1h[ks*4+gt]);
                MFMA(acc[1][gt], a1, w1h[ks*4+gt]);
            }
        }
#pragma unroll
        for (int ks = 0; ks < 4; ++ks) {
            int cc = ks*4 + quad;
            bf16x8 a0 = *(const bf16x8*)&h1s[lrow*128      + ((cc ^ lrow)*8)];
            bf16x8 a1 = *(const bf16x8*)&h1s[(16+lrow)*128 + ((cc ^ lrow)*8)];
#pragma unroll
            for (int gt = 0; gt < 4; ++gt) {
                bf16x8 bf = *(const bf16x8*)&wl[ut*8192 + (ks*4+gt)*512 + lane*8];
                MFMA(acc[0][gt], a0, bf);
                MFMA(acc[1][gt], a1, bf);
            }
        }
        __syncthreads();   // all h0s/h1s reads done before h1s rewrite

        // ---- elementwise L1 -> h1s (no barrier needed after) ----
#pragma unroll
        for (int m = 0; m < 2; ++m) {
#pragma unroll
            for (int r = 0; r < 4; ++r) {
                float ig = sigm(acc[m][0][r]);
                float fg = sigm(acc[m][1][r]);
                float gg = tanhf_(acc[m][2][r]);
                float og = sigm(acc[m][3][r]);
                float c  = fg * c1[m][r] + ig * gg;
                c1[m][r] = c;
                float h  = og * tanhf_(c);
                int b = m*16 + quad*4 + r;
                int j = ut*16 + lrow;
                h1s[b*128 + (((j>>3) ^ (b&15))*8) + (j&7)] = f2bf(h);
            }
        }
    }

    __syncthreads();   // final h1 visible

    // ---- FC (10x128) + log_softmax ----
    if (tid < 320) {
        int c = tid >> 5, b = tid & 31;
        float s = bfc[c];
        const float* wr = Wfc + c*H;
#pragma unroll 4
        for (int j = 0; j < H; ++j)
            s = fmaf(wr[j], bf2f(h1s[b*128 + (((j>>3) ^ (b&15))*8) + (j&7)]), s);
        lg[c*32 + b] = s;
    }
    __syncthreads();
    if (tid < 32) {
        int b = tid;
        float m = -1e30f;
#pragma unroll
        for (int c = 0; c < 10; ++c) m = fmaxf(m, lg[c*32 + b]);
        float ssum = 0.f;
#pragma unroll
        for (int c = 0; c < 10; ++c) ssum += __expf(lg[c*32 + b] - m);
        float ls = m + __logf(ssum);
        float* op = out + (size_t)(bbase + b) * 10;
#pragma unroll
        for (int c = 0; c < 10; ++c) op[c] = lg[c*32 + b] - ls;
    }
}

extern "C" void kernel_launch(void* const* d_in, const int* in_sizes, int n_in,
                              void* d_out, int out_size, void* d_ws, size_t ws_size,
                              hipStream_t stream) {
    const float* x    = (const float*)d_in[0];
    const float* Wih0 = (const float*)d_in[1];
    const float* Whh0 = (const float*)d_in[2];
    const float* bih0 = (const float*)d_in[3];
    const float* bhh0 = (const float*)d_in[4];
    const float* Wih1 = (const float*)d_in[5];
    const float* Whh1 = (const float*)d_in[6];
    const float* bih1 = (const float*)d_in[7];
    const float* bhh1 = (const float*)d_in[8];
    const float* Wfc  = (const float*)d_in[9];
    const float* bfc  = (const float*)d_in[10];
    float* out = (float*)d_out;

    unsigned short* W = (unsigned short*)d_ws;
    float* bias = (float*)((char*)d_ws + BIAS_OFF_BYTES);

    const int n_prep = NW0E + NW1E + 1024;
    prep<<<(n_prep + 255) / 256, 256, 0, stream>>>(Wih0, Whh0, bih0, bhh0,
                                                   Wih1, Whh1, bih1, bhh1, W, bias);
    lstm_mfma<<<8192 / BT, NTHR, 0, stream>>>(x, W, bias, Wfc, bfc, out);
}